// Round 1
// baseline (359.481 us; speedup 1.0000x reference)
//
#include <hip/hip_runtime.h>

#define NUM_K 1024
#define DIM 256
#define HW 1024
#define BETA 0.25f
#define NTOT 8388608  // 32*256*32*32

// d_ws layout (floats): [0] loss accumulator, [64 .. 64+1024) e-norms

__global__ void prep_kernel(const float* __restrict__ wgt, float* __restrict__ ws) {
    int wave = threadIdx.x >> 6, lane = threadIdx.x & 63;
    int k = blockIdx.x * 4 + wave;
    if (blockIdx.x == 0 && threadIdx.x == 0) ws[0] = 0.f;
    const float4 v = *reinterpret_cast<const float4*>(wgt + (size_t)k * DIM + lane * 4);
    float s = v.x * v.x + v.y * v.y + v.z * v.z + v.w * v.w;
    #pragma unroll
    for (int off = 32; off > 0; off >>= 1) s += __shfl_down(s, off, 64);
    if (lane == 0) ws[64 + k] = s;
}

__launch_bounds__(256, 2)
__global__ void vq_kernel(const float* __restrict__ in, const float* __restrict__ wgt,
                          const float* __restrict__ enorm, float* __restrict__ loss_acc,
                          float* __restrict__ out) {
    __shared__ float xs[128 * 64];  // xs[d][row], 32 KB
    __shared__ float es[128 * 64];  // es[d][code^swz], 32 KB
    const int tid = threadIdx.x;
    const int tx = tid & 15, ty = tid >> 4;
    const int bid = blockIdx.x;
    const int bb = bid >> 4;            // batch index
    const int hw0 = (bid & 15) << 6;    // 64 rows (hw positions) per block
    const float* inb = in + (size_t)bb * DIM * HW + hw0;

    float minv[4] = {1e30f, 1e30f, 1e30f, 1e30f};
    int mini[4] = {0, 0, 0, 0};

    for (int kc = 0; kc < 16; ++kc) {
        float acc[4][4] = {{0.f}};
        for (int dh = 0; dh < 2; ++dh) {
            __syncthreads();
            // stage x tile (transposed): xs[dl*64 + i] = x[row hw0+i][dh*128+dl]
            {
                int i4 = (tid & 15) << 2;
                int dl0 = tid >> 4;
                #pragma unroll
                for (int p = 0; p < 8; ++p) {
                    int dl = dl0 + p * 16;
                    float4 v = *reinterpret_cast<const float4*>(
                        inb + (size_t)(dh * 128 + dl) * HW + i4);
                    *reinterpret_cast<float4*>(&xs[dl * 64 + i4]) = v;
                }
            }
            // stage codebook tile transposed + XOR-swizzled:
            // element (code c, dim d=4*d4+q) at es[d*64 + (c ^ ((d4&7)<<2))]
            {
                int d4 = tid & 31;
                int c0 = tid >> 5;
                int swz = (d4 & 7) << 2;
                #pragma unroll
                for (int p = 0; p < 8; ++p) {
                    int c = c0 + p * 8;
                    float4 v = *reinterpret_cast<const float4*>(
                        wgt + (size_t)(kc * 64 + c) * DIM + dh * 128 + (d4 << 2));
                    int cs = c ^ swz;
                    es[(d4 * 4 + 0) * 64 + cs] = v.x;
                    es[(d4 * 4 + 1) * 64 + cs] = v.y;
                    es[(d4 * 4 + 2) * 64 + cs] = v.z;
                    es[(d4 * 4 + 3) * 64 + cs] = v.w;
                }
            }
            __syncthreads();
            #pragma unroll 2
            for (int d = 0; d < 128; ++d) {
                float4 a = *reinterpret_cast<const float4*>(&xs[d * 64 + (ty << 2)]);
                int swz = ((d >> 2) & 7) << 2;
                float4 bv = *reinterpret_cast<const float4*>(&es[d * 64 + ((tx << 2) ^ swz)]);
                acc[0][0] += a.x * bv.x; acc[0][1] += a.x * bv.y;
                acc[0][2] += a.x * bv.z; acc[0][3] += a.x * bv.w;
                acc[1][0] += a.y * bv.x; acc[1][1] += a.y * bv.y;
                acc[1][2] += a.y * bv.z; acc[1][3] += a.y * bv.w;
                acc[2][0] += a.z * bv.x; acc[2][1] += a.z * bv.y;
                acc[2][2] += a.z * bv.z; acc[2][3] += a.z * bv.w;
                acc[3][0] += a.w * bv.x; acc[3][1] += a.w * bv.y;
                acc[3][2] += a.w * bv.z; acc[3][3] += a.w * bv.w;
            }
        }
        // running argmin update (dist = ||e||^2 - 2 x.e ; row const ||x||^2 dropped)
        float4 env = *reinterpret_cast<const float4*>(enorm + kc * 64 + (tx << 2));
        float en[4] = {env.x, env.y, env.z, env.w};
        #pragma unroll
        for (int i = 0; i < 4; ++i) {
            #pragma unroll
            for (int j = 0; j < 4; ++j) {
                float dst = en[j] - 2.f * acc[i][j];
                if (dst < minv[i]) { minv[i] = dst; mini[i] = kc * 64 + (tx << 2) + j; }
            }
        }
    }
    // reduce across the 16 tx lanes (same rows), tie-break on smaller index
    #pragma unroll
    for (int i = 0; i < 4; ++i) {
        float v = minv[i]; int ix = mini[i];
        #pragma unroll
        for (int off = 1; off < 16; off <<= 1) {
            float ov = __shfl_xor(v, off, 64);
            int oi = __shfl_xor(ix, off, 64);
            if (ov < v || (ov == v && oi < ix)) { v = ov; ix = oi; }
        }
        minv[i] = v; mini[i] = ix;
    }
    __syncthreads();
    int* idx_s = reinterpret_cast<int*>(xs);
    if (tx == 0) {
        #pragma unroll
        for (int i = 0; i < 4; ++i) idx_s[ty * 4 + i] = mini[i];
    }
    __syncthreads();
    // epilogue: gather code row, write quantized (coalesced), accumulate loss
    float lsum = 0.f;
    {
        int i = tid & 63;           // row within tile
        int d0 = tid >> 6;          // wave id 0..3
        int myk = idx_s[i];
        const float* erow = wgt + (size_t)myk * DIM;
        float* outb = out + (size_t)bb * DIM * HW + hw0;
        #pragma unroll 4
        for (int m = 0; m < 64; ++m) {
            int d = d0 + (m << 2);
            float ev = erow[d];
            float xv = inb[(size_t)d * HW + i];
            outb[(size_t)d * HW + i] = ev;
            float df = ev - xv;
            lsum += df * df;
        }
    }
    #pragma unroll
    for (int off = 32; off > 0; off >>= 1) lsum += __shfl_down(lsum, off, 64);
    if ((tid & 63) == 0) atomicAdd(loss_acc, lsum);
}

__global__ void loss_kernel(const float* __restrict__ ws, float* __restrict__ out_loss) {
    out_loss[0] = (1.f + BETA) * ws[0] / (float)NTOT;
}

extern "C" void kernel_launch(void* const* d_in, const int* in_sizes, int n_in,
                              void* d_out, int out_size, void* d_ws, size_t ws_size,
                              hipStream_t stream) {
    const float* enc = (const float*)d_in[0];
    const float* wgt = (const float*)d_in[1];
    float* out = (float*)d_out;
    float* ws = (float*)d_ws;

    prep_kernel<<<NUM_K / 4, 256, 0, stream>>>(wgt, ws);
    vq_kernel<<<512, 256, 0, stream>>>(enc, wgt, ws + 64, ws, out);
    loss_kernel<<<1, 1, 0, stream>>>(ws, out + NTOT);
}

// Round 2
// 81.246 us; speedup vs baseline: 4.4246x; 4.4246x over previous
//
#include <hip/hip_runtime.h>

#define NUM_K 1024
#define DIM 256
#define HWDIM 1024
#define BETA 0.25f
#define NTOT 8388608  // 32*256*32*32

typedef __attribute__((ext_vector_type(8))) short short8;
typedef __attribute__((ext_vector_type(4))) float fx4;

// d_ws layout (floats): [0] loss acc | [64..1088) enorm | [1088..) bf16 codebook (1024x256 ushort)

__device__ __forceinline__ unsigned short f2bf(float f) {
    unsigned int b = __builtin_bit_cast(unsigned int, f);
    return (unsigned short)((b + 0x7FFFu + ((b >> 16) & 1u)) >> 16);  // RNE
}

__global__ void prep_kernel(const float* __restrict__ wgt, float* __restrict__ ws) {
    int wave = threadIdx.x >> 6, lane = threadIdx.x & 63;
    int k = blockIdx.x * 4 + wave;
    if (blockIdx.x == 0 && threadIdx.x == 0) ws[0] = 0.f;
    const float4 v = *reinterpret_cast<const float4*>(wgt + (size_t)k * DIM + lane * 4);
    float s = v.x * v.x + v.y * v.y + v.z * v.z + v.w * v.w;
    #pragma unroll
    for (int off = 32; off > 0; off >>= 1) s += __shfl_down(s, off, 64);
    if (lane == 0) ws[64 + k] = s;
    unsigned short* ebf = reinterpret_cast<unsigned short*>(ws + 1088);
    ushort4 p;
    p.x = f2bf(v.x); p.y = f2bf(v.y); p.z = f2bf(v.z); p.w = f2bf(v.w);
    *reinterpret_cast<ushort4*>(ebf + (size_t)k * DIM + lane * 4) = p;
}

// swizzled ushort index into xs[64][256]: spreads rows across 16B slots
__device__ __forceinline__ int xsw(int row, int d) {
    return (row * 256 + d) ^ (((row ^ (row >> 3)) & 7) << 3);
}

__launch_bounds__(256, 2)
__global__ void vq_kernel(const float* __restrict__ in,
                          const float* __restrict__ wgt,
                          float* __restrict__ ws,
                          float* __restrict__ out) {
    __shared__ unsigned short xs[64 * 256];   // 32 KB, bf16 x-tile [row][d] swizzled
    __shared__ float cand_v[4][64];
    __shared__ int   cand_i[4][64];
    __shared__ int   idx_s[64];

    const float* enorm = ws + 64;
    const unsigned short* ebf = reinterpret_cast<const unsigned short*>(ws + 1088);

    const int tid = threadIdx.x;
    const int lane = tid & 63;
    const int wv = tid >> 6;        // wave 0..3: owns codes [wv*256, wv*256+256)
    const int tx = lane & 15;
    const int tz = lane >> 4;
    const int bid = blockIdx.x;
    const int bb = bid >> 4;            // batch
    const int hw0 = (bid & 15) << 6;    // 64 hw positions
    const float* inb = in + (size_t)bb * (DIM * HWDIM) + hw0;

    // ---- stage x tile: fp32 [d][hw] global -> bf16 [row][d] LDS (swizzled) ----
    {
        int hw4 = (tid & 15) << 2;   // 4 rows per thread
        int dp = tid >> 4;           // d-pair id 0..15
        #pragma unroll
        for (int it = 0; it < 8; ++it) {
            int d = dp * 2 + it * 32;
            float4 v0 = *reinterpret_cast<const float4*>(inb + (size_t)d * HWDIM + hw4);
            float4 v1 = *reinterpret_cast<const float4*>(inb + (size_t)(d + 1) * HWDIM + hw4);
            unsigned int p0 = (unsigned)f2bf(v0.x) | ((unsigned)f2bf(v1.x) << 16);
            unsigned int p1 = (unsigned)f2bf(v0.y) | ((unsigned)f2bf(v1.y) << 16);
            unsigned int p2 = (unsigned)f2bf(v0.z) | ((unsigned)f2bf(v1.z) << 16);
            unsigned int p3 = (unsigned)f2bf(v0.w) | ((unsigned)f2bf(v1.w) << 16);
            *reinterpret_cast<unsigned int*>(&xs[xsw(hw4 + 0, d)]) = p0;
            *reinterpret_cast<unsigned int*>(&xs[xsw(hw4 + 1, d)]) = p1;
            *reinterpret_cast<unsigned int*>(&xs[xsw(hw4 + 2, d)]) = p2;
            *reinterpret_cast<unsigned int*>(&xs[xsw(hw4 + 3, d)]) = p3;
        }
    }
    __syncthreads();

    // ---- hoist A fragments: row = rf*16 + tx, k = s*32 + tz*8 + [0..7] ----
    short8 af[4][8];
    #pragma unroll
    for (int rf = 0; rf < 4; ++rf) {
        #pragma unroll
        for (int s = 0; s < 8; ++s)
            af[rf][s] = *reinterpret_cast<const short8*>(&xs[xsw(rf * 16 + tx, s * 32 + tz * 8)]);
    }

    float minv[16];
    int   mini[16];
    #pragma unroll
    for (int q = 0; q < 16; ++q) { minv[q] = 1e30f; mini[q] = 0; }

    for (int ch = 0; ch < 16; ++ch) {
        const int mycode = wv * 256 + ch * 16 + tx;   // B col = tx
        short8 bf[8];
        #pragma unroll
        for (int s = 0; s < 8; ++s)
            bf[s] = *reinterpret_cast<const short8*>(ebf + (size_t)mycode * DIM + s * 32 + tz * 8);
        fx4 z = {0.f, 0.f, 0.f, 0.f};
        fx4 acc[4];
        #pragma unroll
        for (int rf = 0; rf < 4; ++rf) acc[rf] = z;
        #pragma unroll
        for (int s = 0; s < 8; ++s) {
            #pragma unroll
            for (int rf = 0; rf < 4; ++rf)
                acc[rf] = __builtin_amdgcn_mfma_f32_16x16x32_bf16(af[rf][s], bf[s], acc[rf], 0, 0, 0);
        }
        float en = enorm[mycode];
        #pragma unroll
        for (int rf = 0; rf < 4; ++rf) {
            #pragma unroll
            for (int r = 0; r < 4; ++r) {
                float dist = en - 2.f * acc[rf][r];   // row-const ||x||^2 dropped
                int q = rf * 4 + r;
                if (dist < minv[q]) { minv[q] = dist; mini[q] = mycode; }
            }
        }
    }

    // ---- reduce over the 16 col-lanes (tie-break: smaller index) ----
    #pragma unroll
    for (int q = 0; q < 16; ++q) {
        float v = minv[q]; int ix = mini[q];
        #pragma unroll
        for (int off = 1; off < 16; off <<= 1) {
            float ov = __shfl_xor(v, off, 64);
            int   oi = __shfl_xor(ix, off, 64);
            if (ov < v || (ov == v && oi < ix)) { v = ov; ix = oi; }
        }
        minv[q] = v; mini[q] = ix;
    }
    if (tx == 0) {
        #pragma unroll
        for (int rf = 0; rf < 4; ++rf) {
            #pragma unroll
            for (int r = 0; r < 4; ++r) {
                int row = rf * 16 + tz * 4 + r;       // C row = (lane>>4)*4 + reg
                cand_v[wv][row] = minv[rf * 4 + r];
                cand_i[wv][row] = mini[rf * 4 + r];
            }
        }
    }
    __syncthreads();
    if (tid < 64) {
        float bv = cand_v[0][tid]; int bi = cand_i[0][tid];
        #pragma unroll
        for (int w = 1; w < 4; ++w) {
            float v = cand_v[w][tid]; int ix = cand_i[w][tid];
            if (v < bv || (v == bv && ix < bi)) { bv = v; bi = ix; }
        }
        idx_s[tid] = bi;
    }
    __syncthreads();

    // ---- epilogue: gather fp32 code row, write coalesced, loss ----
    {
        int hw = tid & 63;
        int w4 = tid >> 6;                 // d quarter 0..3
        int myk = idx_s[hw];
        const float* erow = wgt + (size_t)myk * DIM + w4 * 64;
        float* outb = out + (size_t)bb * (DIM * HWDIM) + hw0;
        float lsum = 0.f;
        #pragma unroll 4
        for (int m = 0; m < 16; ++m) {
            float4 e4 = *reinterpret_cast<const float4*>(erow + m * 4);
            float ev[4] = {e4.x, e4.y, e4.z, e4.w};
            #pragma unroll
            for (int qd = 0; qd < 4; ++qd) {
                int d = w4 * 64 + m * 4 + qd;
                float xv = inb[(size_t)d * HWDIM + hw];
                outb[(size_t)d * HWDIM + hw] = ev[qd];
                float df = ev[qd] - xv;
                lsum += df * df;
            }
        }
        #pragma unroll
        for (int off = 32; off > 0; off >>= 1) lsum += __shfl_down(lsum, off, 64);
        if (lane == 0) atomicAdd(&ws[0], lsum);
    }
}

__global__ void loss_kernel(const float* __restrict__ ws, float* __restrict__ out_loss) {
    out_loss[0] = (1.f + BETA) * ws[0] / (float)NTOT;
}

extern "C" void kernel_launch(void* const* d_in, const int* in_sizes, int n_in,
                              void* d_out, int out_size, void* d_ws, size_t ws_size,
                              hipStream_t stream) {
    const float* enc = (const float*)d_in[0];
    const float* wgt = (const float*)d_in[1];
    float* out = (float*)d_out;
    float* ws = (float*)d_ws;

    prep_kernel<<<NUM_K / 4, 256, 0, stream>>>(wgt, ws);
    vq_kernel<<<512, 256, 0, stream>>>(enc, wgt, ws, out);
    loss_kernel<<<1, 1, 0, stream>>>(ws, out + NTOT);
}

// Round 3
// 71.095 us; speedup vs baseline: 5.0563x; 1.1428x over previous
//
#include <hip/hip_runtime.h>

#define NUM_K 1024
#define DIM 256
#define HWDIM 1024
#define BETA 0.25f
#define NTOT 8388608  // 32*256*32*32
#define DIST_C 0.25f  // makes dist = ||e||^2 + C - 2 x.e always positive (|2x.e| << 0.25)

typedef __attribute__((ext_vector_type(8))) short short8;
typedef __attribute__((ext_vector_type(4))) float fx4;

// d_ws layout (floats): [0] loss acc | [64..1088) enorm+C | [1088..) bf16 codebook (1024x256 ushort)

__device__ __forceinline__ unsigned short f2bf(float f) {
    unsigned int b = __builtin_bit_cast(unsigned int, f);
    return (unsigned short)((b + 0x7FFFu + ((b >> 16) & 1u)) >> 16);  // RNE
}

__global__ void prep_kernel(const float* __restrict__ wgt, float* __restrict__ ws) {
    int wave = threadIdx.x >> 6, lane = threadIdx.x & 63;
    int k = blockIdx.x * 4 + wave;
    if (blockIdx.x == 0 && threadIdx.x == 0) ws[0] = 0.f;
    const float4 v = *reinterpret_cast<const float4*>(wgt + (size_t)k * DIM + lane * 4);
    float s = v.x * v.x + v.y * v.y + v.z * v.z + v.w * v.w;
    #pragma unroll
    for (int off = 32; off > 0; off >>= 1) s += __shfl_down(s, off, 64);
    if (lane == 0) ws[64 + k] = s + DIST_C;
    unsigned short* ebf = reinterpret_cast<unsigned short*>(ws + 1088);
    ushort4 p;
    p.x = f2bf(v.x); p.y = f2bf(v.y); p.z = f2bf(v.z); p.w = f2bf(v.w);
    *reinterpret_cast<ushort4*>(ebf + (size_t)k * DIM + lane * 4) = p;
}

// swizzled ushort index into xs[64][256]
__device__ __forceinline__ int xsw(int row, int d) {
    return (row * 256 + d) ^ (((row ^ (row >> 3)) & 7) << 3);
}

__device__ __forceinline__ void load_b(short8 (&buf)[8], float& en,
                                       const unsigned short* ebfw,
                                       const float* enormC, int code) {
    const unsigned short* p = ebfw + (size_t)code * DIM;
    #pragma unroll
    for (int s = 0; s < 8; ++s)
        buf[s] = *reinterpret_cast<const short8*>(p + s * 32);
    en = enormC[code];
}

__device__ __forceinline__ void process(const short8 (&af)[4][8], const short8 (&buf)[8],
                                        float en, int code, float (&minkey)[16]) {
    fx4 acc[4];
    const fx4 z = {0.f, 0.f, 0.f, 0.f};
    #pragma unroll
    for (int rf = 0; rf < 4; ++rf) acc[rf] = z;
    __builtin_amdgcn_s_setprio(1);
    #pragma unroll
    for (int s = 0; s < 8; ++s) {
        #pragma unroll
        for (int rf = 0; rf < 4; ++rf)
            acc[rf] = __builtin_amdgcn_mfma_f32_16x16x32_bf16(af[rf][s], buf[s], acc[rf], 0, 0, 0);
    }
    __builtin_amdgcn_s_setprio(0);
    #pragma unroll
    for (int rf = 0; rf < 4; ++rf) {
        #pragma unroll
        for (int r = 0; r < 4; ++r) {
            float d = fmaf(-2.f, acc[rf][r], en);          // positive shifted distance
            unsigned int u = (__builtin_bit_cast(unsigned int, d) & 0xFFFFFC00u) | (unsigned int)code;
            float kf = __builtin_bit_cast(float, u);
            minkey[rf * 4 + r] = fminf(minkey[rf * 4 + r], kf);
        }
    }
}

__launch_bounds__(256, 2)
__global__ void vq_kernel(const float* __restrict__ in,
                          const float* __restrict__ wgt,
                          float* __restrict__ ws,
                          float* __restrict__ out) {
    __shared__ unsigned short xs[64 * 256];   // 32 KB bf16 x-tile [row][d] swizzled
    __shared__ float cand_k[4][64];
    __shared__ int   idx_s[64];

    const float* enormC = ws + 64;
    const unsigned short* ebf = reinterpret_cast<const unsigned short*>(ws + 1088);

    const int tid = threadIdx.x;
    const int lane = tid & 63;
    const int wv = tid >> 6;
    const int tx = lane & 15;
    const int tz = lane >> 4;
    const int wvbase = wv * 256;
    const int bid = blockIdx.x;
    const int bb = bid >> 4;
    const int hw0 = (bid & 15) << 6;
    const float* inb = in + (size_t)bb * (DIM * HWDIM) + hw0;
    const unsigned short* ebfw = ebf + tz * 8;

    short8 bA[8], bB[8];
    float eA, eB;
    load_b(bA, eA, ebfw, enormC, wvbase + tx);   // overlap with x staging

    // ---- stage x: fp32 [d][hw] -> bf16 [row][d] LDS (swizzled) ----
    {
        int hw4 = (tid & 15) << 2;
        int dp = tid >> 4;
        #pragma unroll
        for (int it = 0; it < 8; ++it) {
            int d = dp * 2 + it * 32;
            float4 v0 = *reinterpret_cast<const float4*>(inb + (size_t)d * HWDIM + hw4);
            float4 v1 = *reinterpret_cast<const float4*>(inb + (size_t)(d + 1) * HWDIM + hw4);
            unsigned int p0 = (unsigned)f2bf(v0.x) | ((unsigned)f2bf(v1.x) << 16);
            unsigned int p1 = (unsigned)f2bf(v0.y) | ((unsigned)f2bf(v1.y) << 16);
            unsigned int p2 = (unsigned)f2bf(v0.z) | ((unsigned)f2bf(v1.z) << 16);
            unsigned int p3 = (unsigned)f2bf(v0.w) | ((unsigned)f2bf(v1.w) << 16);
            *reinterpret_cast<unsigned int*>(&xs[xsw(hw4 + 0, d)]) = p0;
            *reinterpret_cast<unsigned int*>(&xs[xsw(hw4 + 1, d)]) = p1;
            *reinterpret_cast<unsigned int*>(&xs[xsw(hw4 + 2, d)]) = p2;
            *reinterpret_cast<unsigned int*>(&xs[xsw(hw4 + 3, d)]) = p3;
        }
    }
    __syncthreads();

    // ---- hoist A fragments (must stay resident: 128 VGPRs) ----
    short8 af[4][8];
    #pragma unroll
    for (int rf = 0; rf < 4; ++rf) {
        #pragma unroll
        for (int s = 0; s < 8; ++s)
            af[rf][s] = *reinterpret_cast<const short8*>(&xs[xsw(rf * 16 + tx, s * 32 + tz * 8)]);
    }
    asm volatile("" ::: "memory");   // pin af/bA values: no remat of loads across this

    float minkey[16];
    #pragma unroll
    for (int q = 0; q < 16; ++q) minkey[q] = 1e30f;

    for (int ch = 0; ch < 16; ch += 2) {
        load_b(bB, eB, ebfw, enormC, wvbase + (ch + 1) * 16 + tx);
        process(af, bA, eA, wvbase + ch * 16 + tx, minkey);
        if (ch < 14) load_b(bA, eA, ebfw, enormC, wvbase + (ch + 2) * 16 + tx);
        process(af, bB, eB, wvbase + (ch + 1) * 16 + tx, minkey);
    }

    // ---- reduce over the 16 col-lanes ----
    #pragma unroll
    for (int q = 0; q < 16; ++q) {
        float v = minkey[q];
        #pragma unroll
        for (int off = 1; off < 16; off <<= 1)
            v = fminf(v, __shfl_xor(v, off, 64));
        minkey[q] = v;
    }
    if (tx == 0) {
        #pragma unroll
        for (int rf = 0; rf < 4; ++rf) {
            #pragma unroll
            for (int r = 0; r < 4; ++r)
                cand_k[wv][rf * 16 + tz * 4 + r] = minkey[rf * 4 + r];
        }
    }
    __syncthreads();
    if (tid < 64) {
        float bv = fminf(fminf(cand_k[0][tid], cand_k[1][tid]),
                         fminf(cand_k[2][tid], cand_k[3][tid]));
        idx_s[tid] = (int)(__builtin_bit_cast(unsigned int, bv) & 0x3FFu);
    }
    __syncthreads();

    // ---- epilogue: float4 gather + coalesced write + loss ----
    {
        int hw4 = (tid & 15) << 2;
        int dq = tid >> 4;                       // 16 d-chunk id
        int k0 = idx_s[hw4 + 0], k1 = idx_s[hw4 + 1];
        int k2 = idx_s[hw4 + 2], k3 = idx_s[hw4 + 3];
        const float* e0 = wgt + (size_t)k0 * DIM;
        const float* e1 = wgt + (size_t)k1 * DIM;
        const float* e2 = wgt + (size_t)k2 * DIM;
        const float* e3 = wgt + (size_t)k3 * DIM;
        float* outb = out + (size_t)bb * (DIM * HWDIM) + hw0;
        float lsum = 0.f;
        #pragma unroll
        for (int m = 0; m < 4; ++m) {
            int d0 = dq * 16 + m * 4;
            float4 r0 = *reinterpret_cast<const float4*>(e0 + d0);
            float4 r1 = *reinterpret_cast<const float4*>(e1 + d0);
            float4 r2 = *reinterpret_cast<const float4*>(e2 + d0);
            float4 r3 = *reinterpret_cast<const float4*>(e3 + d0);
            float er0[4] = {r0.x, r0.y, r0.z, r0.w};
            float er1[4] = {r1.x, r1.y, r1.z, r1.w};
            float er2[4] = {r2.x, r2.y, r2.z, r2.w};
            float er3[4] = {r3.x, r3.y, r3.z, r3.w};
            #pragma unroll
            for (int qd = 0; qd < 4; ++qd) {
                int d = d0 + qd;
                float4 xv = *reinterpret_cast<const float4*>(inb + (size_t)d * HWDIM + hw4);
                float4 ev = {er0[qd], er1[qd], er2[qd], er3[qd]};
                *reinterpret_cast<float4*>(outb + (size_t)d * HWDIM + hw4) = ev;
                float d0f = ev.x - xv.x, d1f = ev.y - xv.y;
                float d2f = ev.z - xv.z, d3f = ev.w - xv.w;
                lsum += d0f * d0f + d1f * d1f + d2f * d2f + d3f * d3f;
            }
        }
        #pragma unroll
        for (int off = 32; off > 0; off >>= 1) lsum += __shfl_down(lsum, off, 64);
        if (lane == 0) atomicAdd(&ws[0], lsum);
    }
}

__global__ void loss_kernel(const float* __restrict__ ws, float* __restrict__ out_loss) {
    out_loss[0] = (1.f + BETA) * ws[0] / (float)NTOT;
}

extern "C" void kernel_launch(void* const* d_in, const int* in_sizes, int n_in,
                              void* d_out, int out_size, void* d_ws, size_t ws_size,
                              hipStream_t stream) {
    const float* enc = (const float*)d_in[0];
    const float* wgt = (const float*)d_in[1];
    float* out = (float*)d_out;
    float* ws = (float*)d_ws;

    prep_kernel<<<NUM_K / 4, 256, 0, stream>>>(wgt, ws);
    vq_kernel<<<512, 256, 0, stream>>>(enc, wgt, ws, out);
    loss_kernel<<<1, 1, 0, stream>>>(ws, out + NTOT);
}

// Round 4
// 62.727 us; speedup vs baseline: 5.7309x; 1.1334x over previous
//
#include <hip/hip_runtime.h>

#define NUM_K 1024
#define DIM 256
#define HWDIM 1024
#define BETA 0.25f
#define NTOT 8388608  // 32*256*32*32
#define DIST_C 0.25f  // keeps dist = ||e||^2 + C - 2 x.e positive

typedef __attribute__((ext_vector_type(8))) short short8;
typedef __attribute__((ext_vector_type(4))) float fx4;
typedef unsigned short u16;
typedef unsigned int u32;

// d_ws (floats): [0] loss acc | [64..1088) enorm+C | [1088..) fragment-ordered bf16 codebook
//   frag layout: [gc=code/16][s=0..7][lane=0..63][e=0..7] ; value = code row (gc*16+(lane&15)),
//   dim = s*32+(lane>>4)*8+e  -> staging and ds_read are both perfectly linear.

__device__ __forceinline__ u16 f2bf(float f) {
    u32 b = __builtin_bit_cast(u32, f);
    return (u16)((b + 0x7FFFu + ((b >> 16) & 1u)) >> 16);  // RNE
}

__global__ void prep_norm(const float* __restrict__ wgt, float* __restrict__ ws) {
    int wave = threadIdx.x >> 6, lane = threadIdx.x & 63;
    int k = blockIdx.x * 4 + wave;
    if (blockIdx.x == 0 && threadIdx.x == 0) ws[0] = 0.f;
    const float4 v = *reinterpret_cast<const float4*>(wgt + (size_t)k * DIM + lane * 4);
    float s = v.x * v.x + v.y * v.y + v.z * v.z + v.w * v.w;
    #pragma unroll
    for (int off = 32; off > 0; off >>= 1) s += __shfl_down(s, off, 64);
    if (lane == 0) ws[64 + k] = s + DIST_C;
}

__global__ void prep_frag(const float* __restrict__ wgt, float* __restrict__ ws) {
    int g = blockIdx.x * 256 + threadIdx.x;       // 0..32767
    int lane = g & 63, s = (g >> 6) & 7, gc = g >> 9;
    int code = gc * 16 + (lane & 15);
    int d0 = s * 32 + (lane >> 4) * 8;
    const float* p = wgt + (size_t)code * DIM + d0;
    float4 a = *reinterpret_cast<const float4*>(p);
    float4 b = *reinterpret_cast<const float4*>(p + 4);
    u16* dst = reinterpret_cast<u16*>(ws + 1088) + (size_t)g * 8;
    ushort4 lo, hi;
    lo.x = f2bf(a.x); lo.y = f2bf(a.y); lo.z = f2bf(a.z); lo.w = f2bf(a.w);
    hi.x = f2bf(b.x); hi.y = f2bf(b.y); hi.z = f2bf(b.z); hi.w = f2bf(b.w);
    *reinterpret_cast<ushort4*>(dst) = lo;
    *reinterpret_cast<ushort4*>(dst + 4) = hi;
}

__device__ __forceinline__ void gl2lds16(const void* g, void* l) {
    __builtin_amdgcn_global_load_lds(
        (const __attribute__((address_space(1))) u32*)g,
        (__attribute__((address_space(3))) u32*)l, 16, 0, 0);
}

// swizzled ushort index into xs[64][256]
__device__ __forceinline__ int xsw(int row, int d) {
    return (row * 256 + d) ^ (((row ^ (row >> 3)) & 7) << 3);
}

__launch_bounds__(256, 2)
__global__ void vq_kernel(const float* __restrict__ in,
                          const float* __restrict__ wgt,
                          float* __restrict__ ws,
                          float* __restrict__ out) {
    // LDS: [0,64K) per-wave B dbuf (wave w: [w*16K, w*16K+8K) and [+8K,+16K))
    //      [32K,64K) also aliases xs (x-tile) -- dead after af-hoist (guarded by barrier+clobber)
    //      [64K,68K) enorm ; [68K..] cand/idx
    __shared__ __align__(16) unsigned char smem[70912];
    u16* xs = reinterpret_cast<u16*>(smem + 32768);
    float* eno = reinterpret_cast<float*>(smem + 65536);
    float (*cand)[64] = reinterpret_cast<float (*)[64]>(smem + 69632);
    int* idxs = reinterpret_cast<int*>(smem + 70656);
    const u16* ebf2 = reinterpret_cast<const u16*>(ws + 1088);

    const int tid = threadIdx.x;
    const int lane = tid & 63;
    const int wv = tid >> 6;
    const int tx = lane & 15;
    const int tz = lane >> 4;
    const int bid = blockIdx.x;
    const int bb = bid >> 4;
    const int hw0 = (bid & 15) << 6;
    const float* inb = in + (size_t)bb * (DIM * HWDIM) + hw0;

    // ---- stage enorm -> LDS ----
    reinterpret_cast<float4*>(eno)[tid] = reinterpret_cast<const float4*>(ws + 64)[tid];

    // ---- stage x: fp32 [d][hw] -> bf16 [row][d] LDS (swizzled) ----
    {
        int hw4 = (tid & 15) << 2;
        int dp = tid >> 4;
        #pragma unroll
        for (int it = 0; it < 8; ++it) {
            int d = dp * 2 + it * 32;
            float4 v0 = *reinterpret_cast<const float4*>(inb + (size_t)d * HWDIM + hw4);
            float4 v1 = *reinterpret_cast<const float4*>(inb + (size_t)(d + 1) * HWDIM + hw4);
            u32 p0 = (u32)f2bf(v0.x) | ((u32)f2bf(v1.x) << 16);
            u32 p1 = (u32)f2bf(v0.y) | ((u32)f2bf(v1.y) << 16);
            u32 p2 = (u32)f2bf(v0.z) | ((u32)f2bf(v1.z) << 16);
            u32 p3 = (u32)f2bf(v0.w) | ((u32)f2bf(v1.w) << 16);
            *reinterpret_cast<u32*>(&xs[xsw(hw4 + 0, d)]) = p0;
            *reinterpret_cast<u32*>(&xs[xsw(hw4 + 1, d)]) = p1;
            *reinterpret_cast<u32*>(&xs[xsw(hw4 + 2, d)]) = p2;
            *reinterpret_cast<u32*>(&xs[xsw(hw4 + 3, d)]) = p3;
        }
    }
    __syncthreads();

    // ---- hoist A fragments: row = rf*16+tx, k = s*32+tz*8+[0..7] ----
    short8 af[4][8];
    #pragma unroll
    for (int rf = 0; rf < 4; ++rf) {
        #pragma unroll
        for (int s = 0; s < 8; ++s)
            af[rf][s] = *reinterpret_cast<const short8*>(&xs[xsw(rf * 16 + tx, s * 32 + tz * 8)]);
    }
    __syncthreads();                 // all waves done reading xs (B bufs alias it)
    asm volatile("" ::: "memory");   // af must stay in regs: LDS below it is overwritten

    // ---- main loop: per-wave LDS double-buffered B, no barriers ----
    u16* buf0 = reinterpret_cast<u16*>(smem + wv * 16384);
    u16* buf1 = buf0 + 4096;
    const unsigned char* gsrc = reinterpret_cast<const unsigned char*>(ebf2)
                                + (size_t)wv * 16 * 8192 + lane * 16;
    auto stage = [&](int ch, u16* buf) {
        const unsigned char* sp = gsrc + ch * 8192;
        unsigned char* dp = reinterpret_cast<unsigned char*>(buf);
        #pragma unroll
        for (int i = 0; i < 8; ++i)
            gl2lds16(sp + i * 1024, dp + i * 1024);
    };
    stage(0, buf0);
    stage(1, buf1);

    float minkey[16];
    #pragma unroll
    for (int q = 0; q < 16; ++q) minkey[q] = 1e30f;

    #pragma unroll
    for (int ch = 0; ch < 16; ++ch) {
        if (ch == 15) asm volatile("s_waitcnt vmcnt(0)" ::: "memory");
        else          asm volatile("s_waitcnt vmcnt(8)" ::: "memory");
        const u16* cb = (ch & 1) ? buf1 : buf0;
        short8 bf[8];
        #pragma unroll
        for (int s = 0; s < 8; ++s)
            bf[s] = *reinterpret_cast<const short8*>(cb + s * 512 + lane * 8);
        fx4 acc[4];
        const fx4 z = {0.f, 0.f, 0.f, 0.f};
        #pragma unroll
        for (int rf = 0; rf < 4; ++rf) acc[rf] = z;
        __builtin_amdgcn_s_setprio(1);
        #pragma unroll
        for (int s = 0; s < 8; ++s) {
            #pragma unroll
            for (int rf = 0; rf < 4; ++rf)
                acc[rf] = __builtin_amdgcn_mfma_f32_16x16x32_bf16(af[rf][s], bf[s], acc[rf], 0, 0, 0);
        }
        __builtin_amdgcn_s_setprio(0);
        if (ch < 14) stage(ch + 2, (ch & 1) ? buf1 : buf0);
        float en = eno[wv * 256 + ch * 16 + tx];
        const u32 codebase = (u32)(wv * 256 + ch * 16 + tx);
        #pragma unroll
        for (int rf = 0; rf < 4; ++rf) {
            #pragma unroll
            for (int r = 0; r < 4; ++r) {
                float d = fmaf(-2.f, acc[rf][r], en);
                u32 u = (__builtin_bit_cast(u32, d) & 0xFFFFFC00u) | codebase;
                int q = rf * 4 + r;
                minkey[q] = fminf(minkey[q], __builtin_bit_cast(float, u));
            }
        }
    }

    // ---- reduce over the 16 col-lanes ----
    #pragma unroll
    for (int q = 0; q < 16; ++q) {
        float v = minkey[q];
        #pragma unroll
        for (int off = 1; off < 16; off <<= 1)
            v = fminf(v, __shfl_xor(v, off, 64));
        minkey[q] = v;
    }
    if (tx == 0) {
        #pragma unroll
        for (int rf = 0; rf < 4; ++rf) {
            #pragma unroll
            for (int r = 0; r < 4; ++r)
                cand[wv][rf * 16 + tz * 4 + r] = minkey[rf * 4 + r];
        }
    }
    __syncthreads();
    if (tid < 64) {
        float bv = fminf(fminf(cand[0][tid], cand[1][tid]),
                         fminf(cand[2][tid], cand[3][tid]));
        idxs[tid] = (int)(__builtin_bit_cast(u32, bv) & 0x3FFu);
    }
    __syncthreads();

    // ---- epilogue: float4 gather + coalesced write + loss ----
    {
        int hw4 = (tid & 15) << 2;
        int dq = tid >> 4;
        int k0 = idxs[hw4 + 0], k1 = idxs[hw4 + 1];
        int k2 = idxs[hw4 + 2], k3 = idxs[hw4 + 3];
        const float* e0 = wgt + (size_t)k0 * DIM;
        const float* e1 = wgt + (size_t)k1 * DIM;
        const float* e2 = wgt + (size_t)k2 * DIM;
        const float* e3 = wgt + (size_t)k3 * DIM;
        float* outb = out + (size_t)bb * (DIM * HWDIM) + hw0;
        float lsum = 0.f;
        #pragma unroll
        for (int m = 0; m < 4; ++m) {
            int d0 = dq * 16 + m * 4;
            float4 r0 = *reinterpret_cast<const float4*>(e0 + d0);
            float4 r1 = *reinterpret_cast<const float4*>(e1 + d0);
            float4 r2 = *reinterpret_cast<const float4*>(e2 + d0);
            float4 r3 = *reinterpret_cast<const float4*>(e3 + d0);
            float er0[4] = {r0.x, r0.y, r0.z, r0.w};
            float er1[4] = {r1.x, r1.y, r1.z, r1.w};
            float er2[4] = {r2.x, r2.y, r2.z, r2.w};
            float er3[4] = {r3.x, r3.y, r3.z, r3.w};
            #pragma unroll
            for (int qd = 0; qd < 4; ++qd) {
                int d = d0 + qd;
                float4 xv = *reinterpret_cast<const float4*>(inb + (size_t)d * HWDIM + hw4);
                float4 ev = {er0[qd], er1[qd], er2[qd], er3[qd]};
                *reinterpret_cast<float4*>(outb + (size_t)d * HWDIM + hw4) = ev;
                float d0f = ev.x - xv.x, d1f = ev.y - xv.y;
                float d2f = ev.z - xv.z, d3f = ev.w - xv.w;
                lsum += d0f * d0f + d1f * d1f + d2f * d2f + d3f * d3f;
            }
        }
        #pragma unroll
        for (int off = 32; off > 0; off >>= 1) lsum += __shfl_down(lsum, off, 64);
        if (lane == 0) atomicAdd(&ws[0], lsum);
    }
}

__global__ void loss_kernel(const float* __restrict__ ws, float* __restrict__ out_loss) {
    out_loss[0] = (1.f + BETA) * ws[0] / (float)NTOT;
}

extern "C" void kernel_launch(void* const* d_in, const int* in_sizes, int n_in,
                              void* d_out, int out_size, void* d_ws, size_t ws_size,
                              hipStream_t stream) {
    const float* enc = (const float*)d_in[0];
    const float* wgt = (const float*)d_in[1];
    float* out = (float*)d_out;
    float* ws = (float*)d_ws;

    prep_norm<<<NUM_K / 4, 256, 0, stream>>>(wgt, ws);
    prep_frag<<<128, 256, 0, stream>>>(wgt, ws);
    vq_kernel<<<512, 256, 0, stream>>>(enc, wgt, ws, out);
    loss_kernel<<<1, 1, 0, stream>>>(ws, out + NTOT);
}